// Round 1
// baseline (930.010 us; speedup 1.0000x reference)
//
#include <hip/hip_runtime.h>

#define N_NODES 100000
#define N_EDGES 1000000
#define IN_F 128
#define OUT_F 128
#define NUM_RELS 64

// ---------------------------------------------------------------------------
// Kernel A: out[n][o] = bias[o] + sum_k h[n][k] * W[k][o]
// 256 threads/block; block computes a 128-node x 128-out tile.
// thread (ty=tid>>4, tx=tid&15): nodes ty*8+j, outs tx*8+i, 8x8 register tile.
// All operands from global: h read exactly once (reuse via wave broadcast),
// W (64KB) stays L2-resident.
// ---------------------------------------------------------------------------
__global__ __launch_bounds__(256) void gemm_selfloop(
    const float* __restrict__ h, const float* __restrict__ W,
    const float* __restrict__ bias, float* __restrict__ out, int n_nodes)
{
    const int tid = threadIdx.x;
    const int ty = tid >> 4, tx = tid & 15;
    const int node0 = blockIdx.x * 128 + ty * 8;
    const int o0 = tx * 8;

    float acc[8][8];
#pragma unroll
    for (int j = 0; j < 8; ++j)
#pragma unroll
        for (int i = 0; i < 8; ++i) acc[j][i] = 0.f;

    int nidx[8];
#pragma unroll
    for (int j = 0; j < 8; ++j) {
        int n = node0 + j;
        nidx[j] = n < n_nodes ? n : (n_nodes - 1); // clamp for safe loads
    }

    for (int k = 0; k < IN_F; k += 4) {
        float hsv[8][4];
#pragma unroll
        for (int j = 0; j < 8; ++j) {
            float4 hv = *reinterpret_cast<const float4*>(h + (size_t)nidx[j] * IN_F + k);
            *reinterpret_cast<float4*>(hsv[j]) = hv;
        }
#pragma unroll
        for (int kk = 0; kk < 4; ++kk) {
            const float* wrow = W + (size_t)(k + kk) * OUT_F + o0;
            float wr[8];
            *reinterpret_cast<float4*>(wr)     = *reinterpret_cast<const float4*>(wrow);
            *reinterpret_cast<float4*>(wr + 4) = *reinterpret_cast<const float4*>(wrow + 4);
#pragma unroll
            for (int j = 0; j < 8; ++j) {
                const float hk = hsv[j][kk];
#pragma unroll
                for (int i = 0; i < 8; ++i)
                    acc[j][i] = fmaf(hk, wr[i], acc[j][i]);
            }
        }
    }

    float br[8];
    *reinterpret_cast<float4*>(br)     = *reinterpret_cast<const float4*>(bias + o0);
    *reinterpret_cast<float4*>(br + 4) = *reinterpret_cast<const float4*>(bias + o0 + 4);

#pragma unroll
    for (int j = 0; j < 8; ++j) {
        int n = node0 + j;
        if (n < n_nodes) {
            float4 v0, v1;
            v0.x = acc[j][0] + br[0]; v0.y = acc[j][1] + br[1];
            v0.z = acc[j][2] + br[2]; v0.w = acc[j][3] + br[3];
            v1.x = acc[j][4] + br[4]; v1.y = acc[j][5] + br[5];
            v1.z = acc[j][6] + br[6]; v1.w = acc[j][7] + br[7];
            float* op = out + (size_t)n * OUT_F + o0;
            *reinterpret_cast<float4*>(op)     = v0;
            *reinterpret_cast<float4*>(op + 4) = v1;
        }
    }
}

// ---------------------------------------------------------------------------
// Kernel B: per-edge BDD message + atomic scatter-add into out[dst].
// One wave (64 lanes) per edge; 4 edges per 256-thread block.
// lane -> block b = lane>>2 (0..15), output pair jp = (lane&3)*2.
//   msg[b*8+jp+{0,1}] = norm * sum_i h[src][b*8+i] * w[r][b*64 + i*8 + jp+{0,1}]
// ---------------------------------------------------------------------------
__global__ __launch_bounds__(256) void edge_msg_atomic(
    const float* __restrict__ h, const float* __restrict__ norm,
    const float* __restrict__ weight,
    const int* __restrict__ src, const int* __restrict__ dst,
    const int* __restrict__ rel,
    float* __restrict__ out, int n_edges)
{
    const int lane = threadIdx.x & 63;
    const int wid  = threadIdx.x >> 6;
    const int e = blockIdx.x * 4 + wid;
    if (e >= n_edges) return;

    const int s = src[e];
    const int d = dst[e];
    const int rr = rel[e];
    const float nrm = norm[e];

    const int b  = lane >> 2;        // 0..15
    const int jp = (lane & 3) << 1;  // 0,2,4,6

    // 8 source features for this block
    float hs[8];
    const float4* hrow = reinterpret_cast<const float4*>(h + (size_t)s * IN_F + b * 8);
    *reinterpret_cast<float4*>(hs)     = hrow[0];
    *reinterpret_cast<float4*>(hs + 4) = hrow[1];

    const float* wbase = weight + (size_t)rr * 1024 + b * 64 + jp;
    float m0 = 0.f, m1 = 0.f;
#pragma unroll
    for (int i = 0; i < 8; ++i) {
        float2 wv = *reinterpret_cast<const float2*>(wbase + i * 8);
        m0 = fmaf(hs[i], wv.x, m0);
        m1 = fmaf(hs[i], wv.y, m1);
    }

    float* op = out + (size_t)d * OUT_F + b * 8 + jp;
    atomicAdd(op,     m0 * nrm);
    atomicAdd(op + 1, m1 * nrm);
}

// ---------------------------------------------------------------------------
// Kernel C: in-place ReLU over out (float4-vectorized).
// ---------------------------------------------------------------------------
__global__ __launch_bounds__(256) void relu_inplace(float* __restrict__ out, int n4)
{
    int i = blockIdx.x * blockDim.x + threadIdx.x;
    if (i < n4) {
        float4 v = reinterpret_cast<float4*>(out)[i];
        v.x = fmaxf(v.x, 0.f);
        v.y = fmaxf(v.y, 0.f);
        v.z = fmaxf(v.z, 0.f);
        v.w = fmaxf(v.w, 0.f);
        reinterpret_cast<float4*>(out)[i] = v;
    }
}

extern "C" void kernel_launch(void* const* d_in, const int* in_sizes, int n_in,
                              void* d_out, int out_size, void* d_ws, size_t ws_size,
                              hipStream_t stream)
{
    const float* h      = (const float*)d_in[0];
    const float* norm   = (const float*)d_in[1];
    const float* weight = (const float*)d_in[2];
    const float* loop_w = (const float*)d_in[3];
    const float* bias   = (const float*)d_in[4];
    const int*   src    = (const int*)d_in[5];
    const int*   dst    = (const int*)d_in[6];
    const int*   rel    = (const int*)d_in[7];
    float* out = (float*)d_out;

    // A: out = h @ loop_weight + bias
    gemm_selfloop<<<(N_NODES + 127) / 128, 256, 0, stream>>>(h, loop_w, bias, out, N_NODES);
    // B: out += scatter-sum of per-edge messages
    edge_msg_atomic<<<(N_EDGES + 3) / 4, 256, 0, stream>>>(h, norm, weight, src, dst, rel, out, N_EDGES);
    // C: out = relu(out)
    relu_inplace<<<(N_NODES * OUT_F / 4 + 255) / 256, 256, 0, stream>>>(out, N_NODES * OUT_F / 4);
}

// Round 2
// 504.742 us; speedup vs baseline: 1.8425x; 1.8425x over previous
//
#include <hip/hip_runtime.h>

#define N_NODES 100000
#define N_EDGES 1000000
#define IN_F 128
#define OUT_F 128
#define NUM_RELS 64
#define NB_SCAN ((N_NODES + 255) / 256)   // 391 blocks for the scan

// ---------------------------------------------------------------------------
// Kernel A: out[n][o] = bias[o] + sum_k h[n][k] * W[k][o]   (self-loop GEMM)
// 256 threads/block; block computes a 128-node x 128-out tile, 8x8 reg tile.
// ---------------------------------------------------------------------------
__global__ __launch_bounds__(256) void gemm_selfloop(
    const float* __restrict__ h, const float* __restrict__ W,
    const float* __restrict__ bias, float* __restrict__ out, int n_nodes)
{
    const int tid = threadIdx.x;
    const int ty = tid >> 4, tx = tid & 15;
    const int node0 = blockIdx.x * 128 + ty * 8;
    const int o0 = tx * 8;

    float acc[8][8];
#pragma unroll
    for (int j = 0; j < 8; ++j)
#pragma unroll
        for (int i = 0; i < 8; ++i) acc[j][i] = 0.f;

    int nidx[8];
#pragma unroll
    for (int j = 0; j < 8; ++j) {
        int n = node0 + j;
        nidx[j] = n < n_nodes ? n : (n_nodes - 1);
    }

    for (int k = 0; k < IN_F; k += 4) {
        float hsv[8][4];
#pragma unroll
        for (int j = 0; j < 8; ++j) {
            float4 hv = *reinterpret_cast<const float4*>(h + (size_t)nidx[j] * IN_F + k);
            *reinterpret_cast<float4*>(hsv[j]) = hv;
        }
#pragma unroll
        for (int kk = 0; kk < 4; ++kk) {
            const float* wrow = W + (size_t)(k + kk) * OUT_F + o0;
            float wr[8];
            *reinterpret_cast<float4*>(wr)     = *reinterpret_cast<const float4*>(wrow);
            *reinterpret_cast<float4*>(wr + 4) = *reinterpret_cast<const float4*>(wrow + 4);
#pragma unroll
            for (int j = 0; j < 8; ++j) {
                const float hk = hsv[j][kk];
#pragma unroll
                for (int i = 0; i < 8; ++i)
                    acc[j][i] = fmaf(hk, wr[i], acc[j][i]);
            }
        }
    }

    float br[8];
    *reinterpret_cast<float4*>(br)     = *reinterpret_cast<const float4*>(bias + o0);
    *reinterpret_cast<float4*>(br + 4) = *reinterpret_cast<const float4*>(bias + o0 + 4);

#pragma unroll
    for (int j = 0; j < 8; ++j) {
        int n = node0 + j;
        if (n < n_nodes) {
            float4 v0, v1;
            v0.x = acc[j][0] + br[0]; v0.y = acc[j][1] + br[1];
            v0.z = acc[j][2] + br[2]; v0.w = acc[j][3] + br[3];
            v1.x = acc[j][4] + br[4]; v1.y = acc[j][5] + br[5];
            v1.z = acc[j][6] + br[6]; v1.w = acc[j][7] + br[7];
            float* op = out + (size_t)n * OUT_F + o0;
            *reinterpret_cast<float4*>(op)     = v0;
            *reinterpret_cast<float4*>(op + 4) = v1;
        }
    }
}

// ---------------------------------------------------------------------------
// CSR build: histogram -> scan (3 kernels) -> fill (gathers src/rel/norm into
// dst-grouped order so the hot kernel reads them contiguously).
// ---------------------------------------------------------------------------
__global__ __launch_bounds__(256) void hist_dst(
    const int* __restrict__ dst, int* __restrict__ cnt, int n_edges)
{
    int e = blockIdx.x * 256 + threadIdx.x;
    if (e < n_edges) atomicAdd(&cnt[dst[e]], 1);
}

__global__ __launch_bounds__(256) void block_sums(
    const int* __restrict__ cnt, int* __restrict__ part, int n)
{
    __shared__ int sdata[256];
    int i = blockIdx.x * 256 + threadIdx.x;
    sdata[threadIdx.x] = (i < n) ? cnt[i] : 0;
    __syncthreads();
    for (int s = 128; s > 0; s >>= 1) {
        if (threadIdx.x < s) sdata[threadIdx.x] += sdata[threadIdx.x + s];
        __syncthreads();
    }
    if (threadIdx.x == 0) part[blockIdx.x] = sdata[0];
}

// single block, 512 threads: exclusive scan of NB_SCAN (<=512) partials
__global__ __launch_bounds__(512) void scan_partials(int* __restrict__ part, int nb)
{
    __shared__ int buf[512];
    int tid = threadIdx.x;
    int v = (tid < nb) ? part[tid] : 0;
    buf[tid] = v;
    __syncthreads();
    for (int ofs = 1; ofs < 512; ofs <<= 1) {
        int t = (tid >= ofs) ? buf[tid - ofs] : 0;
        __syncthreads();
        buf[tid] += t;
        __syncthreads();
    }
    if (tid < nb) part[tid] = buf[tid] - v;   // exclusive
}

// per-block exclusive scan + block offset -> off[]; also init cur[] and off[N]
__global__ __launch_bounds__(256) void write_off(
    const int* __restrict__ cnt, const int* __restrict__ part,
    int* __restrict__ off, int* __restrict__ cur, int n, int n_edges)
{
    __shared__ int buf[256];
    int tid = threadIdx.x;
    int i = blockIdx.x * 256 + tid;
    int v = (i < n) ? cnt[i] : 0;
    buf[tid] = v;
    __syncthreads();
    for (int ofs = 1; ofs < 256; ofs <<= 1) {
        int t = (tid >= ofs) ? buf[tid - ofs] : 0;
        __syncthreads();
        buf[tid] += t;
        __syncthreads();
    }
    int excl = buf[tid] - v + part[blockIdx.x];
    if (i < n) { off[i] = excl; cur[i] = excl; }
    if (i == n - 1) off[n] = n_edges;
}

__global__ __launch_bounds__(256) void fill_csr(
    const int* __restrict__ src, const int* __restrict__ dst,
    const int* __restrict__ rel, const float* __restrict__ norm,
    int* __restrict__ cur,
    int* __restrict__ esrc2, int* __restrict__ erel2, float* __restrict__ enorm2,
    int n_edges)
{
    int e = blockIdx.x * 256 + threadIdx.x;
    if (e < n_edges) {
        int d = dst[e];
        int p = atomicAdd(&cur[d], 1);
        esrc2[p]  = src[e];
        erel2[p]  = rel[e];
        enorm2[p] = norm[e];
    }
}

// ---------------------------------------------------------------------------
// Hot kernel: one wave per dst node. Accumulate all incoming BDD messages in
// registers (2 outputs/lane), then fuse += selfloop (already in out) + ReLU.
// lane -> block b = lane>>2, jp = (lane&3)*2; output index = lane*2 (+0,+1).
// ---------------------------------------------------------------------------
__global__ __launch_bounds__(256) void gather_nodes(
    const float* __restrict__ h, const float* __restrict__ weight,
    const int* __restrict__ off,
    const int* __restrict__ esrc2, const int* __restrict__ erel2,
    const float* __restrict__ enorm2,
    float* __restrict__ out, int n_nodes)
{
    const int lane = threadIdx.x & 63;
    const int wid  = threadIdx.x >> 6;
    const int d = blockIdx.x * 4 + wid;
    if (d >= n_nodes) return;

    const int beg = off[d];
    const int end = off[d + 1];
    const int b  = lane >> 2;
    const int jp = (lane & 3) << 1;

    float a0 = 0.f, a1 = 0.f;
    for (int j = beg; j < end; ++j) {
        const int   s  = esrc2[j];
        const int   r  = erel2[j];
        const float nm = enorm2[j];

        float hs[8];
        const float4* hrow = reinterpret_cast<const float4*>(h + (size_t)s * IN_F + b * 8);
        *reinterpret_cast<float4*>(hs)     = hrow[0];
        *reinterpret_cast<float4*>(hs + 4) = hrow[1];

        const float* wb = weight + (size_t)r * 1024 + b * 64 + jp;
        float m0 = 0.f, m1 = 0.f;
#pragma unroll
        for (int i = 0; i < 8; ++i) {
            float2 wv = *reinterpret_cast<const float2*>(wb + i * 8);
            m0 = fmaf(hs[i], wv.x, m0);
            m1 = fmaf(hs[i], wv.y, m1);
        }
        a0 = fmaf(m0, nm, a0);
        a1 = fmaf(m1, nm, a1);
    }

    float* op = out + (size_t)d * OUT_F + lane * 2;
    float2 base = *reinterpret_cast<float2*>(op);
    float2 res;
    res.x = fmaxf(base.x + a0, 0.f);
    res.y = fmaxf(base.y + a1, 0.f);
    *reinterpret_cast<float2*>(op) = res;
}

extern "C" void kernel_launch(void* const* d_in, const int* in_sizes, int n_in,
                              void* d_out, int out_size, void* d_ws, size_t ws_size,
                              hipStream_t stream)
{
    const float* h      = (const float*)d_in[0];
    const float* norm   = (const float*)d_in[1];
    const float* weight = (const float*)d_in[2];
    const float* loop_w = (const float*)d_in[3];
    const float* bias   = (const float*)d_in[4];
    const int*   src    = (const int*)d_in[5];
    const int*   dst    = (const int*)d_in[6];
    const int*   rel    = (const int*)d_in[7];
    float* out = (float*)d_out;

    // ws layout (ints unless noted): cnt[N], off[N+1], cur[N], part[NB_SCAN],
    // esrc2[E], erel2[E], enorm2[E] (float)  -> ~13.2 MB
    char* wsb = (char*)d_ws;
    int*   cnt    = (int*)wsb;                       wsb += sizeof(int) * N_NODES;
    int*   off    = (int*)wsb;                       wsb += sizeof(int) * (N_NODES + 1);
    int*   cur    = (int*)wsb;                       wsb += sizeof(int) * N_NODES;
    int*   part   = (int*)wsb;                       wsb += sizeof(int) * 512;
    int*   esrc2  = (int*)wsb;                       wsb += sizeof(int) * N_EDGES;
    int*   erel2  = (int*)wsb;                       wsb += sizeof(int) * N_EDGES;
    float* enorm2 = (float*)wsb;                     wsb += sizeof(float) * N_EDGES;

    hipMemsetAsync(cnt, 0, sizeof(int) * N_NODES, stream);

    const int egrid = (N_EDGES + 255) / 256;
    hist_dst<<<egrid, 256, 0, stream>>>(dst, cnt, N_EDGES);
    block_sums<<<NB_SCAN, 256, 0, stream>>>(cnt, part, N_NODES);
    scan_partials<<<1, 512, 0, stream>>>(part, NB_SCAN);
    write_off<<<NB_SCAN, 256, 0, stream>>>(cnt, part, off, cur, N_NODES, N_EDGES);
    fill_csr<<<egrid, 256, 0, stream>>>(src, dst, rel, norm, cur, esrc2, erel2, enorm2, N_EDGES);

    // self-loop GEMM (bias included) -> out
    gemm_selfloop<<<(N_NODES + 127) / 128, 256, 0, stream>>>(h, loop_w, bias, out, N_NODES);
    // per-dst register accumulation + fused ReLU
    gather_nodes<<<(N_NODES + 3) / 4, 256, 0, stream>>>(
        h, weight, off, esrc2, erel2, enorm2, out, N_NODES);
}